// Round 1
// baseline (660.388 us; speedup 1.0000x reference)
//
#include <hip/hip_runtime.h>
#include <math.h>

#define CDIM 256
#define HDIM 512
#define KCLS 20
#define MAXSEG 8

// ---------------------------------------------------------------------------
// K1: ragged per-segment column sums.  sums[s][c] = sum over rows in seg s.
// 256 threads: rsub = tid>>6 (row within 4-row group), c4 = tid&63 (float4 col).
// Each block owns a contiguous chunk of 4-row groups -> segment index is
// monotonic per thread -> register accumulator + flush-on-change (atomicAdd).
// ---------------------------------------------------------------------------
__global__ __launch_bounds__(256) void seg_sum_kernel(
    const float* __restrict__ feat, const int* __restrict__ offset,
    float* __restrict__ sums, int n, int nseg) {
  int t = threadIdx.x;
  int rsub = t >> 6;
  int c4 = t & 63;

  long total4 = ((long)n + 3) >> 2;
  long per = (total4 + gridDim.x - 1) / gridDim.x;
  long g0 = (long)blockIdx.x * per;
  long g1 = g0 + per;
  if (g1 > total4) g1 = total4;

  int off[MAXSEG];
#pragma unroll
  for (int s = 0; s < MAXSEG; ++s) off[s] = (s < nseg) ? offset[s] : 0x7fffffff;

  const float4* feat4 = (const float4*)feat;
  float4 acc = make_float4(0.f, 0.f, 0.f, 0.f);
  int cur_seg = -1;

  for (long g = g0; g < g1; ++g) {
    long r = g * 4 + rsub;
    if (r >= n) break;
    int s = 0;
#pragma unroll
    for (int q = 0; q < MAXSEG - 1; ++q) s += (r >= off[q]) ? 1 : 0;
    if (s >= nseg) s = nseg - 1;
    if (s != cur_seg) {
      if (cur_seg >= 0) {
        float* dst = sums + (size_t)cur_seg * CDIM + c4 * 4;
        atomicAdd(dst + 0, acc.x);
        atomicAdd(dst + 1, acc.y);
        atomicAdd(dst + 2, acc.z);
        atomicAdd(dst + 3, acc.w);
      }
      acc = make_float4(0.f, 0.f, 0.f, 0.f);
      cur_seg = s;
    }
    float4 f = feat4[r * (CDIM / 4) + c4];
    acc.x += f.x; acc.y += f.y; acc.z += f.z; acc.w += f.w;
  }
  if (cur_seg >= 0) {
    float* dst = sums + (size_t)cur_seg * CDIM + c4 * 4;
    atomicAdd(dst + 0, acc.x);
    atomicAdd(dst + 1, acc.y);
    atomicAdd(dst + 2, acc.z);
    atomicAdd(dst + 3, acc.w);
  }
}

// ---------------------------------------------------------------------------
// K2: LSTM cell with zero initial state.
// gates = pooled @ W_ih^T + b_ih + b_hh ; c = sig(i)*tanh(g); h = sig(o)*tanh(c)
// grid = nseg*2 blocks of 256 threads; each thread computes one h[s][j].
// ---------------------------------------------------------------------------
__global__ __launch_bounds__(256) void lstm_kernel(
    const float* __restrict__ sums, const int* __restrict__ offset,
    const float* __restrict__ W_ih, const float* __restrict__ b_ih,
    const float* __restrict__ b_hh, float* __restrict__ h) {
  __shared__ float pooled[CDIM];
  int s = blockIdx.x >> 1;
  int j = ((blockIdx.x & 1) << 8) + threadIdx.x;  // 0..511
  int prev = (s == 0) ? 0 : offset[s - 1];
  float cnt = (float)(offset[s] - prev);
  pooled[threadIdx.x] = sums[(size_t)s * CDIM + threadIdx.x] / cnt;
  __syncthreads();

  const float* Wi = W_ih + (size_t)(0 * HDIM + j) * CDIM;
  const float* Wg = W_ih + (size_t)(2 * HDIM + j) * CDIM;
  const float* Wo = W_ih + (size_t)(3 * HDIM + j) * CDIM;
  float di = b_ih[0 * HDIM + j] + b_hh[0 * HDIM + j];
  float dg = b_ih[2 * HDIM + j] + b_hh[2 * HDIM + j];
  float dd = b_ih[3 * HDIM + j] + b_hh[3 * HDIM + j];
  for (int c = 0; c < CDIM; ++c) {
    float p = pooled[c];
    di = fmaf(p, Wi[c], di);
    dg = fmaf(p, Wg[c], dg);
    dd = fmaf(p, Wo[c], dd);
  }
  float ig = 1.f / (1.f + expf(-di));
  float gg = tanhf(dg);
  float og = 1.f / (1.f + expf(-dd));
  float cc = ig * gg;
  h[(size_t)s * HDIM + j] = og * tanhf(cc);
}

// ---------------------------------------------------------------------------
// K3: ctx = h @ W_proj^T + b_proj ; addvec[s][k] = b_head[k] + ctx[s].W_head[k]
// grid = nseg blocks of 256 threads.
// ---------------------------------------------------------------------------
__global__ __launch_bounds__(256) void ctx_kernel(
    const float* __restrict__ h, const float* __restrict__ W_proj,
    const float* __restrict__ b_proj, const float* __restrict__ W_head,
    const float* __restrict__ b_head, float* __restrict__ addvec) {
  int s = blockIdx.x;
  int t = threadIdx.x;
  __shared__ float hs[HDIM];
  __shared__ float ctx[CDIM];
  hs[t] = h[(size_t)s * HDIM + t];
  hs[t + 256] = h[(size_t)s * HDIM + t + 256];
  __syncthreads();
  const float* Wp = W_proj + (size_t)t * HDIM;
  float acc = b_proj[t];
  for (int j = 0; j < HDIM; ++j) acc = fmaf(hs[j], Wp[j], acc);
  ctx[t] = acc;
  __syncthreads();
  if (t < KCLS) {
    const float* Wh = W_head + (size_t)t * CDIM;
    float a = b_head[t];
    for (int c = 0; c < CDIM; ++c) a = fmaf(ctx[c], Wh[c], a);
    addvec[s * KCLS + t] = a;
  }
}

// ---------------------------------------------------------------------------
// K4: out[n][k] = feat[n] . W_head[k] + addvec[seg(n)][k]
// Thread-per-row; W_head accessed with wave-uniform indices -> scalar loads.
// ---------------------------------------------------------------------------
__global__ __launch_bounds__(256) void head_kernel(
    const float* __restrict__ feat, const int* __restrict__ offset,
    const float* __restrict__ W_head, const float* __restrict__ addvec,
    float* __restrict__ out, int n, int nseg) {
  long r = (long)blockIdx.x * blockDim.x + threadIdx.x;
  if (r >= n) return;

  int off[MAXSEG];
#pragma unroll
  for (int q = 0; q < MAXSEG; ++q) off[q] = (q < nseg) ? offset[q] : 0x7fffffff;
  int s = 0;
#pragma unroll
  for (int q = 0; q < MAXSEG - 1; ++q) s += (r >= off[q]) ? 1 : 0;
  if (s >= nseg) s = nseg - 1;

  const float4* frow = (const float4*)(feat + r * CDIM);
  float acc[KCLS];
#pragma unroll
  for (int k = 0; k < KCLS; ++k) acc[k] = addvec[s * KCLS + k];

#pragma unroll 4
  for (int c4 = 0; c4 < CDIM / 4; ++c4) {
    float4 f = frow[c4];
#pragma unroll
    for (int k = 0; k < KCLS; ++k) {
      const float* w = W_head + k * CDIM + c4 * 4;  // wave-uniform -> s_load
      acc[k] = fmaf(f.x, w[0], acc[k]);
      acc[k] = fmaf(f.y, w[1], acc[k]);
      acc[k] = fmaf(f.z, w[2], acc[k]);
      acc[k] = fmaf(f.w, w[3], acc[k]);
    }
  }

  float* orow = out + r * KCLS;
#pragma unroll
  for (int k = 0; k < KCLS; ++k) orow[k] = acc[k];
}

extern "C" void kernel_launch(void* const* d_in, const int* in_sizes, int n_in,
                              void* d_out, int out_size, void* d_ws, size_t ws_size,
                              hipStream_t stream) {
  const float* feat   = (const float*)d_in[0];
  const int*   offset = (const int*)d_in[1];
  const float* W_ih   = (const float*)d_in[2];
  const float* b_ih   = (const float*)d_in[3];
  // d_in[4] = W_hh : unused (h0 == 0)
  const float* b_hh   = (const float*)d_in[5];
  const float* W_proj = (const float*)d_in[6];
  const float* b_proj = (const float*)d_in[7];
  const float* W_head = (const float*)d_in[8];
  const float* b_head = (const float*)d_in[9];
  float* out = (float*)d_out;

  int n = in_sizes[0] / CDIM;
  int nseg = in_sizes[1];
  if (nseg > MAXSEG) nseg = MAXSEG;

  float* ws     = (float*)d_ws;
  float* sums   = ws;                              // nseg*CDIM
  float* h      = ws + MAXSEG * CDIM;              // nseg*HDIM
  float* addvec = ws + MAXSEG * CDIM + MAXSEG * HDIM;  // nseg*KCLS

  hipMemsetAsync(sums, 0, MAXSEG * CDIM * sizeof(float), stream);
  seg_sum_kernel<<<1024, 256, 0, stream>>>(feat, offset, sums, n, nseg);
  lstm_kernel<<<nseg * 2, 256, 0, stream>>>(sums, offset, W_ih, b_ih, b_hh, h);
  ctx_kernel<<<nseg, 256, 0, stream>>>(h, W_proj, b_proj, W_head, b_head, addvec);
  head_kernel<<<(n + 255) / 256, 256, 0, stream>>>(feat, offset, W_head, addvec,
                                                   out, n, nseg);
}

// Round 2
// 635.165 us; speedup vs baseline: 1.0397x; 1.0397x over previous
//
#include <hip/hip_runtime.h>
#include <math.h>

#define CDIM 256
#define HDIM 512
#define KCLS 20
#define MAXSEG 8
#define TILE_R 64

// ---------------------------------------------------------------------------
// Pass A: single read of feat. Per 64-row tile (XOR-swizzled 64KB LDS):
//   (1) per-segment column sums (thread t owns column t; register accumulate,
//       flush on segment change via atomicAdd — blocks own contiguous ranges
//       so the segment index is monotonic per block)
//   (2) head partial: out[r][k] = feat[r]·W_head[k] + b_head[k]
//       lane = row, wave = 5-class group; W_head via scalar (uniform) loads.
// Swizzle: logical float4 (rr, c4) stored at f4 index rr*64 + (c4 ^ (rr&7)).
//   - staging write: row uniform per wave, lanes contiguous  -> optimal
//   - head read (fixed c4, lanes=rows): XOR spreads over all 8 bank quads
//   - column read (fixed rr, lanes=cols): permutation of 256B -> optimal
// ---------------------------------------------------------------------------
__global__ __launch_bounds__(256) void fused_pool_head_kernel(
    const float* __restrict__ feat, const int* __restrict__ offset,
    const float* __restrict__ W_head, const float* __restrict__ b_head,
    float* __restrict__ sums, float* __restrict__ out, int n, int nseg) {
  __shared__ float tile[TILE_R * CDIM];  // exactly 64 KB
  int t = threadIdx.x;
  int lane = t & 63;
  int wv = t >> 6;
  int kb = __builtin_amdgcn_readfirstlane(wv * 5);  // class base, SGPR

  int ntiles = (n + TILE_R - 1) / TILE_R;
  int per = (ntiles + (int)gridDim.x - 1) / (int)gridDim.x;
  int tl0 = (int)blockIdx.x * per;
  int tl1 = tl0 + per;
  if (tl1 > ntiles) tl1 = ntiles;

  int off[MAXSEG];
#pragma unroll
  for (int q = 0; q < MAXSEG; ++q) off[q] = (q < nseg) ? offset[q] : 0x7fffffff;

  float colacc = 0.f;
  int cur_seg = -1;
  float4* tile4 = (float4*)tile;

  for (int tl = tl0; tl < tl1; ++tl) {
    long r0 = (long)tl * TILE_R;
    int rows = (int)((n - r0) < TILE_R ? (n - r0) : TILE_R);
    const float4* src = (const float4*)(feat + r0 * CDIM);

    if (rows == TILE_R) {
#pragma unroll
      for (int i = 0; i < 16; ++i) {  // 4096 float4 / 256 threads
        int idx = i * 256 + t;
        int rr = idx >> 6, c4 = idx & 63;
        tile4[rr * 64 + (c4 ^ (rr & 7))] = src[idx];
      }
    } else {
      for (int idx = t; idx < rows * 64; idx += 256) {
        int rr = idx >> 6, c4 = idx & 63;
        tile4[rr * 64 + (c4 ^ (rr & 7))] = src[idx];
      }
    }
    __syncthreads();

    // ---- (1) segment column sums ----
    {
      int s0 = 0, s1 = 0;
      long rl = r0 + rows - 1;
#pragma unroll
      for (int q = 0; q < MAXSEG - 1; ++q) {
        s0 += (r0 >= off[q]) ? 1 : 0;
        s1 += (rl >= off[q]) ? 1 : 0;
      }
      if (s0 >= nseg) s0 = nseg - 1;
      if (s1 >= nseg) s1 = nseg - 1;
      int c4s = t >> 2, js = t & 3;
      if (s0 == s1) {  // fast path: tile entirely in one segment
        if (s0 != cur_seg) {
          if (cur_seg >= 0) atomicAdd(&sums[cur_seg * CDIM + t], colacc);
          colacc = 0.f;
          cur_seg = s0;
        }
#pragma unroll 8
        for (int rr = 0; rr < rows; ++rr)
          colacc += tile[(rr * 64 + (c4s ^ (rr & 7))) * 4 + js];
      } else {
        for (int rr = 0; rr < rows; ++rr) {
          long r = r0 + rr;
          int s = 0;
#pragma unroll
          for (int q = 0; q < MAXSEG - 1; ++q) s += (r >= off[q]) ? 1 : 0;
          if (s >= nseg) s = nseg - 1;
          if (s != cur_seg) {
            if (cur_seg >= 0) atomicAdd(&sums[cur_seg * CDIM + t], colacc);
            colacc = 0.f;
            cur_seg = s;
          }
          colacc += tile[(rr * 64 + (c4s ^ (rr & 7))) * 4 + js];
        }
      }
    }

    // ---- (2) head partial ----
    if (lane < rows) {
      float acc[5];
#pragma unroll
      for (int k5 = 0; k5 < 5; ++k5) acc[k5] = b_head[kb + k5];
      const float4* trow = tile4 + lane * 64;
      int l7 = lane & 7;
#pragma unroll 4
      for (int c4 = 0; c4 < 64; ++c4) {
        float4 f = trow[c4 ^ l7];
#pragma unroll
        for (int k5 = 0; k5 < 5; ++k5) {
          const float* w = W_head + (kb + k5) * CDIM + c4 * 4;  // uniform -> s_load
          acc[k5] = fmaf(f.x, w[0], acc[k5]);
          acc[k5] = fmaf(f.y, w[1], acc[k5]);
          acc[k5] = fmaf(f.z, w[2], acc[k5]);
          acc[k5] = fmaf(f.w, w[3], acc[k5]);
        }
      }
      float* orow = out + (r0 + lane) * KCLS + kb;
#pragma unroll
      for (int k5 = 0; k5 < 5; ++k5) orow[k5] = acc[k5];
    }
    __syncthreads();
  }
  if (cur_seg >= 0) atomicAdd(&sums[cur_seg * CDIM + t], colacc);
}

// ---------------------------------------------------------------------------
// LSTM cell, zero initial state. One thread per h[s][j].
// ---------------------------------------------------------------------------
__global__ __launch_bounds__(256) void lstm_kernel(
    const float* __restrict__ sums, const int* __restrict__ offset,
    const float* __restrict__ W_ih, const float* __restrict__ b_ih,
    const float* __restrict__ b_hh, float* __restrict__ h) {
  __shared__ float pooled[CDIM];
  int s = blockIdx.x >> 1;
  int j = ((blockIdx.x & 1) << 8) + threadIdx.x;
  int prev = (s == 0) ? 0 : offset[s - 1];
  float cnt = (float)(offset[s] - prev);
  pooled[threadIdx.x] = sums[(size_t)s * CDIM + threadIdx.x] / cnt;
  __syncthreads();

  const float* Wi = W_ih + (size_t)(0 * HDIM + j) * CDIM;
  const float* Wg = W_ih + (size_t)(2 * HDIM + j) * CDIM;
  const float* Wo = W_ih + (size_t)(3 * HDIM + j) * CDIM;
  float di = b_ih[0 * HDIM + j] + b_hh[0 * HDIM + j];
  float dg = b_ih[2 * HDIM + j] + b_hh[2 * HDIM + j];
  float dd = b_ih[3 * HDIM + j] + b_hh[3 * HDIM + j];
  for (int c = 0; c < CDIM; ++c) {
    float p = pooled[c];
    di = fmaf(p, Wi[c], di);
    dg = fmaf(p, Wg[c], dg);
    dd = fmaf(p, Wo[c], dd);
  }
  float ig = 1.f / (1.f + expf(-di));
  float gg = tanhf(dg);
  float og = 1.f / (1.f + expf(-dd));
  h[(size_t)s * HDIM + j] = og * tanhf(ig * gg);
}

// ---------------------------------------------------------------------------
// ctx = h @ W_proj^T + b_proj ; delta[s][k] = ctx[s]·W_head[k]  (NO b_head —
// already applied in pass A).
// ---------------------------------------------------------------------------
__global__ __launch_bounds__(256) void ctx_kernel(
    const float* __restrict__ h, const float* __restrict__ W_proj,
    const float* __restrict__ b_proj, const float* __restrict__ W_head,
    float* __restrict__ delta) {
  int s = blockIdx.x;
  int t = threadIdx.x;
  __shared__ float hs[HDIM];
  __shared__ float ctx[CDIM];
  hs[t] = h[(size_t)s * HDIM + t];
  hs[t + 256] = h[(size_t)s * HDIM + t + 256];
  __syncthreads();
  const float* Wp = W_proj + (size_t)t * HDIM;
  float acc = b_proj[t];
  for (int j = 0; j < HDIM; ++j) acc = fmaf(hs[j], Wp[j], acc);
  ctx[t] = acc;
  __syncthreads();
  if (t < KCLS) {
    const float* Wh = W_head + (size_t)t * CDIM;
    float a = 0.f;
    for (int c = 0; c < CDIM; ++c) a = fmaf(ctx[c], Wh[c], a);
    delta[s * KCLS + t] = a;
  }
}

// ---------------------------------------------------------------------------
// Pass C: out[r][k] += delta[seg(r)][k], float4-vectorized (20 % 4 == 0 so a
// float4 never crosses a row boundary).
// ---------------------------------------------------------------------------
__global__ __launch_bounds__(256) void add_delta_kernel(
    float* __restrict__ out, const int* __restrict__ offset,
    const float* __restrict__ delta, int n, int nseg) {
  __shared__ float dl[MAXSEG * KCLS];
  int t = threadIdx.x;
  if (t < MAXSEG * KCLS) dl[t] = (t < nseg * KCLS) ? delta[t] : 0.f;
  __syncthreads();

  long e4 = (long)blockIdx.x * 256 + t;
  long tot = (long)n * (KCLS / 4);
  if (e4 >= tot) return;
  long row = e4 / 5;
  int k0 = (int)(e4 - row * 5) * 4;

  int off[MAXSEG];
#pragma unroll
  for (int q = 0; q < MAXSEG; ++q) off[q] = (q < nseg) ? offset[q] : 0x7fffffff;
  int s = 0;
#pragma unroll
  for (int q = 0; q < MAXSEG - 1; ++q) s += (row >= off[q]) ? 1 : 0;
  if (s >= nseg) s = nseg - 1;

  float4 v = ((float4*)out)[e4];
  const float* d = &dl[s * KCLS + k0];
  v.x += d[0];
  v.y += d[1];
  v.z += d[2];
  v.w += d[3];
  ((float4*)out)[e4] = v;
}

extern "C" void kernel_launch(void* const* d_in, const int* in_sizes, int n_in,
                              void* d_out, int out_size, void* d_ws, size_t ws_size,
                              hipStream_t stream) {
  const float* feat   = (const float*)d_in[0];
  const int*   offset = (const int*)d_in[1];
  const float* W_ih   = (const float*)d_in[2];
  const float* b_ih   = (const float*)d_in[3];
  // d_in[4] = W_hh : unused (h0 == 0)
  const float* b_hh   = (const float*)d_in[5];
  const float* W_proj = (const float*)d_in[6];
  const float* b_proj = (const float*)d_in[7];
  const float* W_head = (const float*)d_in[8];
  const float* b_head = (const float*)d_in[9];
  float* out = (float*)d_out;

  int n = in_sizes[0] / CDIM;
  int nseg = in_sizes[1];
  if (nseg > MAXSEG) nseg = MAXSEG;

  float* ws    = (float*)d_ws;
  float* sums  = ws;                                   // MAXSEG*CDIM
  float* h     = ws + MAXSEG * CDIM;                   // MAXSEG*HDIM
  float* delta = ws + MAXSEG * CDIM + MAXSEG * HDIM;   // MAXSEG*KCLS

  hipMemsetAsync(sums, 0, MAXSEG * CDIM * sizeof(float), stream);
  fused_pool_head_kernel<<<512, 256, 0, stream>>>(feat, offset, W_head, b_head,
                                                  sums, out, n, nseg);
  lstm_kernel<<<nseg * 2, 256, 0, stream>>>(sums, offset, W_ih, b_ih, b_hh, h);
  ctx_kernel<<<nseg, 256, 0, stream>>>(h, W_proj, b_proj, W_head, delta);
  long tot4 = (long)n * (KCLS / 4);
  int blocksC = (int)((tot4 + 255) / 256);
  add_delta_kernel<<<blocksC, 256, 0, stream>>>(out, offset, delta, n, nseg);
}

// Round 3
// 425.932 us; speedup vs baseline: 1.5505x; 1.4912x over previous
//
#include <hip/hip_runtime.h>
#include <math.h>

#define CDIM 256
#define HDIM 512
#define KCLS 20
#define MAXSEG 8
#define TILE_R 64
#define NTHR 512
#define F4_TILE (TILE_R * CDIM / 4)   // 4096 float4 per tile
#define F4_THR (F4_TILE / NTHR)       // 8 float4 per thread

// ---------------------------------------------------------------------------
// Pass A: single read of feat, software-pipelined (register-staged):
//   loop: issue global loads for tile t+1 into regs  ->  compute tile t from
//   LDS (column sums + head partial)  ->  barrier  ->  ds_write regs  ->
//   barrier.  HBM latency hides under compute; 2 blocks/CU anti-phase.
// LDS tile XOR-swizzled: logical float4 (rr,c4) at f4 index rr*64+(c4^(rr&7))
//   == byte ^= (row&7)<<4 : conflict-free for row-major b128 reads (lane=row)
//   and 2-way-free for column reads.
// ---------------------------------------------------------------------------
__global__ __launch_bounds__(NTHR, 4) void fused_pool_head_kernel(
    const float* __restrict__ feat, const int* __restrict__ offset,
    const float* __restrict__ W_head, const float* __restrict__ b_head,
    float* __restrict__ sums, float* __restrict__ out, int n, int nseg) {
  __shared__ float tile[TILE_R * CDIM];  // 64 KB
  float4* tile4 = (float4*)tile;
  int t = threadIdx.x;
  int lane = t & 63;
  int wv = t >> 6;

  // class assignment: waves 0-3 -> 3 classes, waves 4-7 -> 2 classes
  int kb_ = (wv < 4) ? wv * 3 : 12 + (wv - 4) * 2;
  int kb = __builtin_amdgcn_readfirstlane(kb_);
  float bh0 = b_head[kb], bh1 = b_head[kb + 1];
  float bh2 = (wv < 4) ? b_head[kb + 2] : 0.f;

  int ntiles = (n + TILE_R - 1) / TILE_R;
  int nb = (int)gridDim.x;
  int t0 = (int)blockIdx.x;

  int off[MAXSEG];
#pragma unroll
  for (int q = 0; q < MAXSEG; ++q) off[q] = (q < nseg) ? offset[q] : 0x7fffffff;

  // column-sum ownership: col = t&255, rows [rhalf, rhalf+32)
  int col = t & 255;
  int rhalf = (t >> 8) * 32;
  int c4s = col >> 2, js = col & 3;
  float colacc = 0.f;
  int cur_seg = -1;

  const float4* src = (const float4*)feat;
  long lim = (long)n * (CDIM / 4);
  float4 stg[F4_THR];

  // ---- prologue: stage first tile ----
  if (t0 < ntiles) {
    long base = (long)t0 * F4_TILE;
    if (base + F4_TILE <= lim) {
#pragma unroll
      for (int i = 0; i < F4_THR; ++i) stg[i] = src[base + i * NTHR + t];
    } else {
#pragma unroll
      for (int i = 0; i < F4_THR; ++i) {
        long idx = base + i * NTHR + t;
        stg[i] = (idx < lim) ? src[idx] : make_float4(0.f, 0.f, 0.f, 0.f);
      }
    }
#pragma unroll
    for (int i = 0; i < F4_THR; ++i) {
      int idx = i * NTHR + t;
      int rr = idx >> 6, c4 = idx & 63;
      tile4[rr * 64 + (c4 ^ (rr & 7))] = stg[i];
    }
  }
  __syncthreads();

  for (int tl = t0; tl < ntiles; tl += nb) {
    int nxt = tl + nb;
    bool havenext = (nxt < ntiles);
    long r0 = (long)tl * TILE_R;
    int rows = (int)(((long)n - r0) < TILE_R ? ((long)n - r0) : TILE_R);

    // ---- issue next tile's global loads (overlap with compute below) ----
    if (havenext) {
      long base = (long)nxt * F4_TILE;
      if (base + F4_TILE <= lim) {
#pragma unroll
        for (int i = 0; i < F4_THR; ++i) stg[i] = src[base + i * NTHR + t];
      } else {
#pragma unroll
        for (int i = 0; i < F4_THR; ++i) {
          long idx = base + i * NTHR + t;
          stg[i] = (idx < lim) ? src[idx] : make_float4(0.f, 0.f, 0.f, 0.f);
        }
      }
    }

    // ---- (1) per-segment column sums on my 32-row half ----
    {
      int rlo = rhalf, rhi = rhalf + 32;
      if (rhi > rows) rhi = rows;
      if (rlo < rhi) {
        long ra = r0 + rlo, rb = r0 + rhi - 1;
        int s0 = 0, s1 = 0;
#pragma unroll
        for (int q = 0; q < MAXSEG - 1; ++q) {
          s0 += (ra >= off[q]) ? 1 : 0;
          s1 += (rb >= off[q]) ? 1 : 0;
        }
        if (s0 == s1) {  // whole half-tile in one segment
          if (s0 != cur_seg) {
            if (cur_seg >= 0) atomicAdd(&sums[cur_seg * CDIM + col], colacc);
            colacc = 0.f;
            cur_seg = s0;
          }
          float a = 0.f;
#pragma unroll 8
          for (int rr = rlo; rr < rhi; ++rr)
            a += tile[(rr * 64 + (c4s ^ (rr & 7))) * 4 + js];
          colacc += a;
        } else {
          for (int rr = rlo; rr < rhi; ++rr) {
            long r = r0 + rr;
            int s = 0;
#pragma unroll
            for (int q = 0; q < MAXSEG - 1; ++q) s += (r >= off[q]) ? 1 : 0;
            if (s != cur_seg) {
              if (cur_seg >= 0) atomicAdd(&sums[cur_seg * CDIM + col], colacc);
              colacc = 0.f;
              cur_seg = s;
            }
            colacc += tile[(rr * 64 + (c4s ^ (rr & 7))) * 4 + js];
          }
        }
      }
    }

    // ---- (2) head partial: out[r][k] = feat[r]·W_head[k] + b_head[k] ----
    if (lane < rows) {
      const float4* trow = tile4 + lane * 64;
      int l7 = lane & 7;
      if (wv < 4) {
        float a0 = bh0, a1 = bh1, a2 = bh2;
        const float* w0 = W_head + (kb + 0) * CDIM;
        const float* w1 = W_head + (kb + 1) * CDIM;
        const float* w2 = W_head + (kb + 2) * CDIM;
#pragma unroll 8
        for (int c4 = 0; c4 < 64; ++c4) {
          float4 f = trow[c4 ^ l7];
          int cb = c4 * 4;
          a0 = fmaf(f.x, w0[cb], a0); a1 = fmaf(f.x, w1[cb], a1); a2 = fmaf(f.x, w2[cb], a2);
          a0 = fmaf(f.y, w0[cb+1], a0); a1 = fmaf(f.y, w1[cb+1], a1); a2 = fmaf(f.y, w2[cb+1], a2);
          a0 = fmaf(f.z, w0[cb+2], a0); a1 = fmaf(f.z, w1[cb+2], a1); a2 = fmaf(f.z, w2[cb+2], a2);
          a0 = fmaf(f.w, w0[cb+3], a0); a1 = fmaf(f.w, w1[cb+3], a1); a2 = fmaf(f.w, w2[cb+3], a2);
        }
        float* orow = out + (r0 + lane) * KCLS + kb;
        orow[0] = a0; orow[1] = a1; orow[2] = a2;
      } else {
        float a0 = bh0, a1 = bh1;
        const float* w0 = W_head + (kb + 0) * CDIM;
        const float* w1 = W_head + (kb + 1) * CDIM;
#pragma unroll 8
        for (int c4 = 0; c4 < 64; ++c4) {
          float4 f = trow[c4 ^ l7];
          int cb = c4 * 4;
          a0 = fmaf(f.x, w0[cb], a0);   a1 = fmaf(f.x, w1[cb], a1);
          a0 = fmaf(f.y, w0[cb+1], a0); a1 = fmaf(f.y, w1[cb+1], a1);
          a0 = fmaf(f.z, w0[cb+2], a0); a1 = fmaf(f.z, w1[cb+2], a1);
          a0 = fmaf(f.w, w0[cb+3], a0); a1 = fmaf(f.w, w1[cb+3], a1);
        }
        float* orow = out + (r0 + lane) * KCLS + kb;
        orow[0] = a0; orow[1] = a1;
      }
    }
    __syncthreads();  // all waves done reading tile; staged loads have landed

    if (havenext) {
#pragma unroll
      for (int i = 0; i < F4_THR; ++i) {
        int idx = i * NTHR + t;
        int rr = idx >> 6, c4 = idx & 63;
        tile4[rr * 64 + (c4 ^ (rr & 7))] = stg[i];
      }
    }
    __syncthreads();
  }
  if (cur_seg >= 0) atomicAdd(&sums[cur_seg * CDIM + col], colacc);
}

// ---------------------------------------------------------------------------
// LSTM cell (h0=c0=0) + projection + delta, fused. One block per segment.
//   h = sig(o)*tanh(sig(i)*tanh(g)),  gates = pooled@W_ih^T + b_ih + b_hh
//   ctx = h@W_proj^T + b_proj ;  delta[s][k] = ctx·W_head[k]   (no b_head)
// ---------------------------------------------------------------------------
__global__ __launch_bounds__(512) void lstm_ctx_kernel(
    const float* __restrict__ sums, const int* __restrict__ offset,
    const float* __restrict__ W_ih, const float* __restrict__ b_ih,
    const float* __restrict__ b_hh, const float* __restrict__ W_proj,
    const float* __restrict__ b_proj, const float* __restrict__ W_head,
    float* __restrict__ delta) {
  __shared__ float pooled[CDIM];
  __shared__ float hs[HDIM];
  __shared__ float ctx[CDIM];
  int s = blockIdx.x;
  int t = threadIdx.x;
  if (t < CDIM) {
    int prev = (s == 0) ? 0 : offset[s - 1];
    float cnt = (float)(offset[s] - prev);
    pooled[t] = sums[(size_t)s * CDIM + t] / cnt;
  }
  __syncthreads();

  {
    const float* Wi = W_ih + (size_t)(0 * HDIM + t) * CDIM;
    const float* Wg = W_ih + (size_t)(2 * HDIM + t) * CDIM;
    const float* Wo = W_ih + (size_t)(3 * HDIM + t) * CDIM;
    float di = b_ih[0 * HDIM + t] + b_hh[0 * HDIM + t];
    float dg = b_ih[2 * HDIM + t] + b_hh[2 * HDIM + t];
    float dd = b_ih[3 * HDIM + t] + b_hh[3 * HDIM + t];
    for (int c = 0; c < CDIM; ++c) {
      float p = pooled[c];
      di = fmaf(p, Wi[c], di);
      dg = fmaf(p, Wg[c], dg);
      dd = fmaf(p, Wo[c], dd);
    }
    float ig = 1.f / (1.f + expf(-di));
    float gg = tanhf(dg);
    float og = 1.f / (1.f + expf(-dd));
    hs[t] = og * tanhf(ig * gg);
  }
  __syncthreads();

  if (t < CDIM) {
    const float* Wp = W_proj + (size_t)t * HDIM;
    float acc = b_proj[t];
    for (int j = 0; j < HDIM; ++j) acc = fmaf(hs[j], Wp[j], acc);
    ctx[t] = acc;
  }
  __syncthreads();

  if (t < KCLS) {
    const float* Wh = W_head + (size_t)t * CDIM;
    float a = 0.f;
    for (int c = 0; c < CDIM; ++c) a = fmaf(ctx[c], Wh[c], a);
    delta[s * KCLS + t] = a;
  }
}

// ---------------------------------------------------------------------------
// Pass C: out[r][k] += delta[seg(r)][k], float4-vectorized.
// ---------------------------------------------------------------------------
__global__ __launch_bounds__(256) void add_delta_kernel(
    float* __restrict__ out, const int* __restrict__ offset,
    const float* __restrict__ delta, int n, int nseg) {
  __shared__ float dl[MAXSEG * KCLS];
  int t = threadIdx.x;
  if (t < MAXSEG * KCLS) dl[t] = (t < nseg * KCLS) ? delta[t] : 0.f;
  __syncthreads();

  long e4 = (long)blockIdx.x * 256 + t;
  long tot = (long)n * (KCLS / 4);
  if (e4 >= tot) return;
  long row = e4 / 5;
  int k0 = (int)(e4 - row * 5) * 4;

  int off[MAXSEG];
#pragma unroll
  for (int q = 0; q < MAXSEG; ++q) off[q] = (q < nseg) ? offset[q] : 0x7fffffff;
  int s = 0;
#pragma unroll
  for (int q = 0; q < MAXSEG - 1; ++q) s += (row >= off[q]) ? 1 : 0;
  if (s >= nseg) s = nseg - 1;

  float4 v = ((float4*)out)[e4];
  const float* d = &dl[s * KCLS + k0];
  v.x += d[0]; v.y += d[1]; v.z += d[2]; v.w += d[3];
  ((float4*)out)[e4] = v;
}

extern "C" void kernel_launch(void* const* d_in, const int* in_sizes, int n_in,
                              void* d_out, int out_size, void* d_ws, size_t ws_size,
                              hipStream_t stream) {
  const float* feat   = (const float*)d_in[0];
  const int*   offset = (const int*)d_in[1];
  const float* W_ih   = (const float*)d_in[2];
  const float* b_ih   = (const float*)d_in[3];
  // d_in[4] = W_hh : unused (h0 == 0)
  const float* b_hh   = (const float*)d_in[5];
  const float* W_proj = (const float*)d_in[6];
  const float* b_proj = (const float*)d_in[7];
  const float* W_head = (const float*)d_in[8];
  const float* b_head = (const float*)d_in[9];
  float* out = (float*)d_out;

  int n = in_sizes[0] / CDIM;
  int nseg = in_sizes[1];
  if (nseg > MAXSEG) nseg = MAXSEG;

  float* ws    = (float*)d_ws;
  float* sums  = ws;                                   // MAXSEG*CDIM
  float* delta = ws + MAXSEG * CDIM;                   // MAXSEG*KCLS

  hipMemsetAsync(sums, 0, MAXSEG * CDIM * sizeof(float), stream);
  fused_pool_head_kernel<<<512, NTHR, 0, stream>>>(feat, offset, W_head, b_head,
                                                   sums, out, n, nseg);
  lstm_ctx_kernel<<<nseg, 512, 0, stream>>>(sums, offset, W_ih, b_ih, b_hh,
                                            W_proj, b_proj, W_head, delta);
  long tot4 = (long)n * (KCLS / 4);
  int blocksC = (int)((tot4 + 255) / 256);
  add_delta_kernel<<<blocksC, 256, 0, stream>>>(out, offset, delta, n, nseg);
}

// Round 4
// 367.504 us; speedup vs baseline: 1.7970x; 1.1590x over previous
//
#include <hip/hip_runtime.h>
#include <math.h>

#define CDIM 256
#define HDIM 512
#define KCLS 20
#define MAXSEG 8
#define TILE_R 64
#define NTHR 512
#define F4_TILE (TILE_R * CDIM / 4)   // 4096 float4 per tile
#define F4_THR (F4_TILE / NTHR)       // 8 float4 per thread
#define GRIDA 512

// ---------------------------------------------------------------------------
// Pass A: single read of feat, 2-deep software pipeline (register-staged).
// Round r: [issue loads tile r+2 -> stgX] [compute tile r from LDS]
//          [barrier] [ds_write stgY (tile r+1) — compiler waits vmcnt(8),
//          leaving tile r+2's 8 loads in flight] [barrier].
// LDS tile XOR-swizzled: float4 (rr,c4) at rr*64 + (c4 ^ (rr&7)).
// ---------------------------------------------------------------------------
__global__ __launch_bounds__(NTHR, 4) void fused_pool_head_kernel(
    const float* __restrict__ feat, const int* __restrict__ offset,
    const float* __restrict__ W_head, const float* __restrict__ b_head,
    float* __restrict__ sums, float* __restrict__ out, int n, int nseg) {
  __shared__ float tile[TILE_R * CDIM];  // 64 KB
  float4* tile4 = (float4*)tile;
  int t = threadIdx.x;
  int lane = t & 63;
  int wv = t >> 6;

  // class assignment: waves 0-3 -> 3 classes, waves 4-7 -> 2 classes
  int kb_ = (wv < 4) ? wv * 3 : 12 + (wv - 4) * 2;
  int kb = __builtin_amdgcn_readfirstlane(kb_);
  float bh0 = b_head[kb], bh1 = b_head[kb + 1];
  float bh2 = (wv < 4) ? b_head[kb + 2] : 0.f;

  int ntiles = (n + TILE_R - 1) / TILE_R;
  int nb = (int)gridDim.x;
  int t0 = (int)blockIdx.x;

  int off[MAXSEG];
#pragma unroll
  for (int q = 0; q < MAXSEG; ++q) off[q] = (q < nseg) ? offset[q] : 0x7fffffff;

  // column-sum ownership: col = t&255, rows [rhalf, rhalf+32)
  int col = t & 255;
  int rhalf = (t >> 8) * 32;
  int c4s = col >> 2, js = col & 3;
  float colacc = 0.f;
  int cur_seg = -1;

  const float4* src = (const float4*)feat;
  long lim = (long)n * (CDIM / 4);
  float4 stgA[F4_THR], stgB[F4_THR];

  auto issue = [&](float4* stg, int tl) {
    long base = (long)tl * F4_TILE;
    if (base + F4_TILE <= lim) {
#pragma unroll
      for (int i = 0; i < F4_THR; ++i) stg[i] = src[base + i * NTHR + t];
    } else {
#pragma unroll
      for (int i = 0; i < F4_THR; ++i) {
        long idx = base + i * NTHR + t;
        stg[i] = (idx < lim) ? src[idx] : make_float4(0.f, 0.f, 0.f, 0.f);
      }
    }
  };
  auto dswrite = [&](const float4* stg) {
#pragma unroll
    for (int i = 0; i < F4_THR; ++i) {
      int idx = i * NTHR + t;
      int rr = idx >> 6, c4 = idx & 63;
      tile4[rr * 64 + (c4 ^ (rr & 7))] = stg[i];
    }
  };
  auto compute = [&](int tl) {
    long r0 = (long)tl * TILE_R;
    int rows = (int)(((long)n - r0) < TILE_R ? ((long)n - r0) : TILE_R);

    // ---- (1) per-segment column sums on my 32-row half ----
    int rlo = rhalf, rhi = rhalf + 32;
    if (rhi > rows) rhi = rows;
    if (rlo < rhi) {
      long ra = r0 + rlo, rb = r0 + rhi - 1;
      int s0 = 0, s1 = 0;
#pragma unroll
      for (int q = 0; q < MAXSEG - 1; ++q) {
        s0 += (ra >= off[q]) ? 1 : 0;
        s1 += (rb >= off[q]) ? 1 : 0;
      }
      if (s0 == s1) {
        if (s0 != cur_seg) {
          if (cur_seg >= 0) atomicAdd(&sums[cur_seg * CDIM + col], colacc);
          colacc = 0.f;
          cur_seg = s0;
        }
        float a = 0.f;
#pragma unroll 8
        for (int rr = rlo; rr < rhi; ++rr)
          a += tile[(rr * 64 + (c4s ^ (rr & 7))) * 4 + js];
        colacc += a;
      } else {
        for (int rr = rlo; rr < rhi; ++rr) {
          long r = r0 + rr;
          int s = 0;
#pragma unroll
          for (int q = 0; q < MAXSEG - 1; ++q) s += (r >= off[q]) ? 1 : 0;
          if (s != cur_seg) {
            if (cur_seg >= 0) atomicAdd(&sums[cur_seg * CDIM + col], colacc);
            colacc = 0.f;
            cur_seg = s;
          }
          colacc += tile[(rr * 64 + (c4s ^ (rr & 7))) * 4 + js];
        }
      }
    }

    // ---- (2) head partial: out[r][k] = feat[r]·W_head[k] + b_head[k] ----
    if (lane < rows) {
      const float4* trow = tile4 + lane * 64;
      int l7 = lane & 7;
      if (wv < 4) {
        float a0 = bh0, a1 = bh1, a2 = bh2;
        const float* w0 = W_head + (kb + 0) * CDIM;
        const float* w1 = W_head + (kb + 1) * CDIM;
        const float* w2 = W_head + (kb + 2) * CDIM;
#pragma unroll 4
        for (int c4 = 0; c4 < 64; ++c4) {
          float4 f = trow[c4 ^ l7];
          int cb = c4 * 4;
          a0 = fmaf(f.x, w0[cb], a0); a1 = fmaf(f.x, w1[cb], a1); a2 = fmaf(f.x, w2[cb], a2);
          a0 = fmaf(f.y, w0[cb+1], a0); a1 = fmaf(f.y, w1[cb+1], a1); a2 = fmaf(f.y, w2[cb+1], a2);
          a0 = fmaf(f.z, w0[cb+2], a0); a1 = fmaf(f.z, w1[cb+2], a1); a2 = fmaf(f.z, w2[cb+2], a2);
          a0 = fmaf(f.w, w0[cb+3], a0); a1 = fmaf(f.w, w1[cb+3], a1); a2 = fmaf(f.w, w2[cb+3], a2);
        }
        float* orow = out + (r0 + lane) * KCLS + kb;
        orow[0] = a0; orow[1] = a1; orow[2] = a2;
      } else {
        float a0 = bh0, a1 = bh1;
        const float* w0 = W_head + (kb + 0) * CDIM;
        const float* w1 = W_head + (kb + 1) * CDIM;
#pragma unroll 4
        for (int c4 = 0; c4 < 64; ++c4) {
          float4 f = trow[c4 ^ l7];
          int cb = c4 * 4;
          a0 = fmaf(f.x, w0[cb], a0);   a1 = fmaf(f.x, w1[cb], a1);
          a0 = fmaf(f.y, w0[cb+1], a0); a1 = fmaf(f.y, w1[cb+1], a1);
          a0 = fmaf(f.z, w0[cb+2], a0); a1 = fmaf(f.z, w1[cb+2], a1);
          a0 = fmaf(f.w, w0[cb+3], a0); a1 = fmaf(f.w, w1[cb+3], a1);
        }
        float* orow = out + (r0 + lane) * KCLS + kb;
        orow[0] = a0; orow[1] = a1;
      }
    }
  };

  // ---- prologue: stage tiles t0 and t0+nb; write t0 into LDS ----
  if (t0 < ntiles) issue(stgA, t0);
  if (t0 + nb < ntiles) issue(stgB, t0 + nb);
  if (t0 < ntiles) dswrite(stgA);   // auto s_waitcnt vmcnt(8): stgB stays in flight
  __syncthreads();

  for (int tl = t0; tl < ntiles; tl += 2 * nb) {
    int tA2 = tl + 2 * nb;  // next occupant of stgA
    if (tA2 < ntiles) issue(stgA, tA2);
    compute(tl);
    __syncthreads();
    int tB = tl + nb;
    if (tB < ntiles) dswrite(stgB);  // waits stgB only (stgA loads newer)
    __syncthreads();
    if (tB < ntiles) {
      int tB2 = tl + 3 * nb;
      if (tB2 < ntiles) issue(stgB, tB2);
      compute(tB);
      __syncthreads();
      if (tA2 < ntiles) dswrite(stgA);
      __syncthreads();
    }
  }
  if (cur_seg >= 0) atomicAdd(&sums[cur_seg * CDIM + col], colacc);
}

// ---------------------------------------------------------------------------
// L1: h[s][j] for j = wave-task. lane = (seg s = l>>3, c-chunk = l&7).
// Coalesced W_ih row reads; 3-step shfl_xor reduce within 8-lane seg groups.
// ---------------------------------------------------------------------------
__global__ __launch_bounds__(256) void lstm_h_kernel(
    const float* __restrict__ sums, const int* __restrict__ offset,
    const float* __restrict__ W_ih, const float* __restrict__ b_ih,
    const float* __restrict__ b_hh, float* __restrict__ h, int nseg) {
  __shared__ float pooled[MAXSEG * CDIM];
  int t = threadIdx.x;
  // build pooled
  {
    int prev = 0;
    for (int s = 0; s < MAXSEG; ++s) {
      int cur = (s < nseg) ? offset[s] : prev;
      float cnt = (float)(cur - prev);
      float inv = (cnt > 0.f) ? 1.f / cnt : 0.f;
      pooled[s * CDIM + t] = sums[s * CDIM + t] * inv;
      prev = cur;
    }
  }
  __syncthreads();

  int wv = t >> 6, l = t & 63;
  int j = (int)blockIdx.x * 4 + wv;         // gate column 0..511
  int s = l >> 3, ch = l & 7;               // seg, c-chunk (32 floats)

  const float4* Wi4 = (const float4*)(W_ih + (size_t)(0 * HDIM + j) * CDIM);
  const float4* Wg4 = (const float4*)(W_ih + (size_t)(2 * HDIM + j) * CDIM);
  const float4* Wo4 = (const float4*)(W_ih + (size_t)(3 * HDIM + j) * CDIM);
  const float4* p4 = (const float4*)(pooled + s * CDIM);

  float di = 0.f, dg = 0.f, dd = 0.f;
#pragma unroll
  for (int i = 0; i < 8; ++i) {
    int c4 = ch * 8 + i;
    float4 p = p4[c4];
    float4 wi = Wi4[c4], wg = Wg4[c4], wo = Wo4[c4];
    di = fmaf(p.x, wi.x, di); di = fmaf(p.y, wi.y, di);
    di = fmaf(p.z, wi.z, di); di = fmaf(p.w, wi.w, di);
    dg = fmaf(p.x, wg.x, dg); dg = fmaf(p.y, wg.y, dg);
    dg = fmaf(p.z, wg.z, dg); dg = fmaf(p.w, wg.w, dg);
    dd = fmaf(p.x, wo.x, dd); dd = fmaf(p.y, wo.y, dd);
    dd = fmaf(p.z, wo.z, dd); dd = fmaf(p.w, wo.w, dd);
  }
#pragma unroll
  for (int m = 1; m < 8; m <<= 1) {
    di += __shfl_xor(di, m);
    dg += __shfl_xor(dg, m);
    dd += __shfl_xor(dd, m);
  }
  if (ch == 0 && s < nseg) {
    di += b_ih[j] + b_hh[j];
    dg += b_ih[2 * HDIM + j] + b_hh[2 * HDIM + j];
    dd += b_ih[3 * HDIM + j] + b_hh[3 * HDIM + j];
    float ig = 1.f / (1.f + expf(-di));
    float gg = tanhf(dg);
    float og = 1.f / (1.f + expf(-dd));
    h[(size_t)s * HDIM + j] = og * tanhf(ig * gg);
  }
}

// ---------------------------------------------------------------------------
// L2: ctx[s][t] = b_proj[t] + h[s]·W_proj[t].  wave-task = t, lane=(s, j-chunk).
// ---------------------------------------------------------------------------
__global__ __launch_bounds__(256) void ctx_kernel(
    const float* __restrict__ h, const float* __restrict__ W_proj,
    const float* __restrict__ b_proj, float* __restrict__ ctx, int nseg) {
  __shared__ float hs[MAXSEG * HDIM];
  int t = threadIdx.x;
  {
    const float4* hsrc = (const float4*)h;
    float4* hdst = (float4*)hs;
#pragma unroll
    for (int i = 0; i < 4; ++i) hdst[i * 256 + t] = hsrc[i * 256 + t];
  }
  __syncthreads();

  int wv = t >> 6, l = t & 63;
  int col = (int)blockIdx.x * 4 + wv;       // ctx column 0..255
  int s = l >> 3, ch = l & 7;               // seg, j-chunk (64 floats)

  const float4* Wp4 = (const float4*)(W_proj + (size_t)col * HDIM);
  const float4* h4 = (const float4*)(hs + s * HDIM);
  float acc = 0.f;
#pragma unroll
  for (int i = 0; i < 16; ++i) {
    int j4 = ch * 16 + i;
    float4 hv = h4[j4];
    float4 w = Wp4[j4];
    acc = fmaf(hv.x, w.x, acc); acc = fmaf(hv.y, w.y, acc);
    acc = fmaf(hv.z, w.z, acc); acc = fmaf(hv.w, w.w, acc);
  }
#pragma unroll
  for (int m = 1; m < 8; m <<= 1) acc += __shfl_xor(acc, m);
  if (ch == 0 && s < nseg) ctx[s * CDIM + col] = acc + b_proj[col];
}

// ---------------------------------------------------------------------------
// L3: delta[s][k] = ctx[s]·W_head[k].  wave-task = k, lane=(s, c-chunk).
// ---------------------------------------------------------------------------
__global__ __launch_bounds__(256) void delta_kernel(
    const float* __restrict__ ctx, const float* __restrict__ W_head,
    float* __restrict__ delta, int nseg) {
  __shared__ float cs[MAXSEG * CDIM];
  int t = threadIdx.x;
  {
    const float4* csrc = (const float4*)ctx;
    float4* cdst = (float4*)cs;
#pragma unroll
    for (int i = 0; i < 2; ++i) cdst[i * 256 + t] = csrc[i * 256 + t];
  }
  __syncthreads();

  int wv = t >> 6, l = t & 63;
  int k = (int)blockIdx.x * 4 + wv;         // class 0..19 (grid 5)
  if (k >= KCLS) return;
  int s = l >> 3, ch = l & 7;

  const float4* Wh4 = (const float4*)(W_head + (size_t)k * CDIM);
  const float4* c4 = (const float4*)(cs + s * CDIM);
  float acc = 0.f;
#pragma unroll
  for (int i = 0; i < 8; ++i) {
    int idx = ch * 8 + i;
    float4 cv = c4[idx];
    float4 w = Wh4[idx];
    acc = fmaf(cv.x, w.x, acc); acc = fmaf(cv.y, w.y, acc);
    acc = fmaf(cv.z, w.z, acc); acc = fmaf(cv.w, w.w, acc);
  }
#pragma unroll
  for (int m = 1; m < 8; m <<= 1) acc += __shfl_xor(acc, m);
  if (ch == 0 && s < nseg) delta[s * KCLS + k] = acc;
}

// ---------------------------------------------------------------------------
// Pass C: out[r][k] += delta[seg(r)][k], float4 grid-stride.
// ---------------------------------------------------------------------------
__global__ __launch_bounds__(256) void add_delta_kernel(
    float* __restrict__ out, const int* __restrict__ offset,
    const float* __restrict__ delta, int n, int nseg) {
  __shared__ float dl[MAXSEG * KCLS];
  int t = threadIdx.x;
  if (t < MAXSEG * KCLS) dl[t] = (t < nseg * KCLS) ? delta[t] : 0.f;
  __syncthreads();

  int off[MAXSEG];
#pragma unroll
  for (int q = 0; q < MAXSEG; ++q) off[q] = (q < nseg) ? offset[q] : 0x7fffffff;

  long tot = (long)n * (KCLS / 4);
  long stride = (long)gridDim.x * 256;
  for (long e4 = (long)blockIdx.x * 256 + t; e4 < tot; e4 += stride) {
    long row = e4 / 5;
    int k0 = (int)(e4 - row * 5) * 4;
    int s = 0;
#pragma unroll
    for (int q = 0; q < MAXSEG - 1; ++q) s += (row >= off[q]) ? 1 : 0;
    float4 v = ((float4*)out)[e4];
    const float* d = &dl[s * KCLS + k0];
    v.x += d[0]; v.y += d[1]; v.z += d[2]; v.w += d[3];
    ((float4*)out)[e4] = v;
  }
}

extern "C" void kernel_launch(void* const* d_in, const int* in_sizes, int n_in,
                              void* d_out, int out_size, void* d_ws, size_t ws_size,
                              hipStream_t stream) {
  const float* feat   = (const float*)d_in[0];
  const int*   offset = (const int*)d_in[1];
  const float* W_ih   = (const float*)d_in[2];
  const float* b_ih   = (const float*)d_in[3];
  // d_in[4] = W_hh : unused (h0 == 0)
  const float* b_hh   = (const float*)d_in[5];
  const float* W_proj = (const float*)d_in[6];
  const float* b_proj = (const float*)d_in[7];
  const float* W_head = (const float*)d_in[8];
  const float* b_head = (const float*)d_in[9];
  float* out = (float*)d_out;

  int n = in_sizes[0] / CDIM;
  int nseg = in_sizes[1];
  if (nseg > MAXSEG) nseg = MAXSEG;

  float* ws    = (float*)d_ws;
  float* sums  = ws;                                    // 8*256
  float* h     = ws + MAXSEG * CDIM;                    // 8*512
  float* ctx   = ws + MAXSEG * CDIM + MAXSEG * HDIM;    // 8*256
  float* delta = ctx + MAXSEG * CDIM;                   // 8*20

  hipMemsetAsync(sums, 0, MAXSEG * CDIM * sizeof(float), stream);
  fused_pool_head_kernel<<<GRIDA, NTHR, 0, stream>>>(feat, offset, W_head, b_head,
                                                     sums, out, n, nseg);
  lstm_h_kernel<<<128, 256, 0, stream>>>(sums, offset, W_ih, b_ih, b_hh, h, nseg);
  ctx_kernel<<<64, 256, 0, stream>>>(h, W_proj, b_proj, ctx, nseg);
  delta_kernel<<<5, 256, 0, stream>>>(ctx, W_head, delta, nseg);
  add_delta_kernel<<<2048, 256, 0, stream>>>(out, offset, delta, n, nseg);
}